// Round 1
// 602.642 us; speedup vs baseline: 1.1759x; 1.1759x over previous
//
#include <hip/hip_runtime.h>
#include <cstdint>
#include <cstddef>

// Problem constants (CohereAttention: T=2048, H=4096, NH=32, NKV=8, HD=128)
#define T_SEQ   2048
#define H_DIM   4096
#define NH_Q    32
#define NKV_H   8
#define HD_     128
#define QKV_N   6144            // (NH + 2*NKV) * HD
#define EPS_F   1e-5f
#define ATT_SCALE 0.08838834764831845f   // 1/sqrt(128)
#define LN_THETA  9.210340371976184f     // ln(10000)

typedef __attribute__((ext_vector_type(8))) short bf16x8;
typedef __attribute__((ext_vector_type(4))) float f32x4;

static __device__ __forceinline__ unsigned short f2bf(float f) {
  union { float f; uint32_t u; } v; v.f = f;
  uint32_t u = v.u;
  u += 0x7fff + ((u >> 16) & 1);        // RNE
  return (unsigned short)(u >> 16);
}
static __device__ __forceinline__ float bf2f(unsigned short h) {
  union { uint32_t u; float f; } v; v.u = ((uint32_t)h) << 16;
  return v.f;
}

// async global->LDS, 16B per lane; LDS dest is wave-uniform base + lane*16
static __device__ __forceinline__ void gld_lds16(const void* g, void* l) {
  __builtin_amdgcn_global_load_lds(
      (const __attribute__((address_space(1))) unsigned int*)g,
      (__attribute__((address_space(3))) unsigned int*)l, 16, 0, 0);
}

// ---------------------------------------------------------------------------
// 1) fp32 -> bf16 elementwise convert (hidden_states)
__global__ void convert_bf16_kernel(const float* __restrict__ in,
                                    unsigned short* __restrict__ out, int n4) {
  int i = blockIdx.x * blockDim.x + threadIdx.x;
  if (i < n4) {
    float4 f = *(const float4*)(in + (size_t)i * 4);
    ushort4 o;
    o.x = f2bf(f.x); o.y = f2bf(f.y); o.z = f2bf(f.z); o.w = f2bf(f.w);
    *(ushort4*)(out + (size_t)i * 4) = o;
  }
}

// ---------------------------------------------------------------------------
// 2) fp32 [R][C] -> bf16 [C][R] transpose-convert (weights -> Bt layout)
__global__ void transpose_bf16_kernel(const float* __restrict__ in,
                                      unsigned short* __restrict__ out,
                                      int R, int C) {
  __shared__ float tile[32][33];
  int c0 = blockIdx.x * 32, r0 = blockIdx.y * 32;
  int tx = threadIdx.x, ty = threadIdx.y;   // blockDim = (32, 8)
  for (int i = 0; i < 32; i += 8)
    tile[ty + i][tx] = in[(size_t)(r0 + ty + i) * C + c0 + tx];
  __syncthreads();
  for (int i = 0; i < 32; i += 8)
    out[(size_t)(c0 + ty + i) * R + r0 + tx] = f2bf(tile[tx][ty + i]);
}

// ---------------------------------------------------------------------------
// 3) GEMM: C[M][N] = A[M][K] * B[K][N], A bf16 row-major, Bt = B^T bf16 [N][K].
//    128x128 block tile, BK=32, 4 waves each computing 64x64 via 4x4 MFMA tiles.
//    m97 structure: async global_load_lds width-16 into LINEAR LDS tiles,
//    2 barriers per K-step (compiler drains vmcnt(0) before s_barrier).
template <bool BF16OUT>
__global__ __launch_bounds__(256) void gemm_bt_kernel(
    const unsigned short* __restrict__ A, const unsigned short* __restrict__ Bt,
    void* __restrict__ Cp, int M, int N, int K) {
  __shared__ unsigned short As[128 * 32];   // linear: global_load_lds needs it
  __shared__ unsigned short Bs[128 * 32];
  const int tid = threadIdx.x;
  const int lane = tid & 63, wid = tid >> 6;
  const int wm = wid & 1, wn = wid >> 1;
  const int m0 = blockIdx.y * 128, n0 = blockIdx.x * 128;
  const int g = lane >> 4, s = lane & 15;
  const int lr = lane >> 2, lc = (lane & 3) * 8;   // 4 lanes x 16B per 64B row

  f32x4 acc[4][4] = {};
  for (int k0 = 0; k0 < K; k0 += 32) {
    __syncthreads();           // all waves done reading As/Bs of prev step
    // wave w stages rows [w*16+j*64 .. +16) of both tiles, 1 KiB per issue
    for (int j = 0; j < 2; j++) {
      const int r = wid * 16 + j * 64 + lr;
      gld_lds16(A  + (size_t)(m0 + r) * K + k0 + lc,
                &As[(wid * 16 + j * 64) * 32]);
      gld_lds16(Bt + (size_t)(n0 + r) * K + k0 + lc,
                &Bs[(wid * 16 + j * 64) * 32]);
    }
    __syncthreads();           // implicit vmcnt(0) drain -> tiles ready
    bf16x8 af[4], bfr[4];
    for (int t = 0; t < 4; t++) {
      af[t]  = *(const bf16x8*)&As[(wm * 64 + t * 16 + s) * 32 + g * 8];
      bfr[t] = *(const bf16x8*)&Bs[(wn * 64 + t * 16 + s) * 32 + g * 8];
    }
    for (int mt = 0; mt < 4; mt++)
      for (int nt = 0; nt < 4; nt++)
        acc[mt][nt] = __builtin_amdgcn_mfma_f32_16x16x32_bf16(
            af[mt], bfr[nt], acc[mt][nt], 0, 0, 0);
  }
  for (int mt = 0; mt < 4; mt++)
    for (int nt = 0; nt < 4; nt++)
      for (int r = 0; r < 4; r++) {
        int m = m0 + wm * 64 + mt * 16 + g * 4 + r;   // C/D: row=(lane>>4)*4+reg
        int n = n0 + wn * 64 + nt * 16 + s;           //      col=lane&15
        float v = acc[mt][nt][r];
        if (BF16OUT) ((unsigned short*)Cp)[(size_t)m * N + n] = f2bf(v);
        else         ((float*)Cp)[(size_t)m * N + n] = v;
      }
}

// ---------------------------------------------------------------------------
// 4) Per-(t,head) LayerNorm + interleaved RoPE, in-place on qkv buffer.
//    One wave per 128-elem row; lane d handles the (2d, 2d+1) pair.
//    Q rows additionally folded with the attention scale.
__global__ __launch_bounds__(256) void ln_rope_kernel(
    unsigned short* __restrict__ qkv, const int* __restrict__ positions,
    const float* __restrict__ qw, const float* __restrict__ kw) {
  const int wid = threadIdx.x >> 6, lane = threadIdx.x & 63;
  const int rid = blockIdx.x * 4 + wid;     // 0 .. T*(NH+NKV)-1
  const int t = rid / 40, hh = rid % 40;
  const bool isq = hh < NH_Q;
  const int col = isq ? hh * HD_ : H_DIM + (hh - NH_Q) * HD_;
  unsigned short* row = qkv + (size_t)t * QKV_N + col;

  uint32_t both = *(const uint32_t*)(row + lane * 2);
  float x1 = bf2f((unsigned short)(both & 0xffff));
  float x2 = bf2f((unsigned short)(both >> 16));
  float ssum = x1 + x2, ssq = x1 * x1 + x2 * x2;
  for (int off = 1; off < 64; off <<= 1) {
    ssum += __shfl_xor(ssum, off, 64);
    ssq  += __shfl_xor(ssq,  off, 64);
  }
  float mean = ssum * (1.0f / HD_);
  float var  = ssq * (1.0f / HD_) - mean * mean;
  float rs = rsqrtf(var + EPS_F);
  const float* w = isq ? (qw + hh * HD_) : (kw + (hh - NH_Q) * HD_);
  float2 wv = *(const float2*)(w + lane * 2);
  float y1 = (x1 - mean) * rs * wv.x;
  float y2 = (x2 - mean) * rs * wv.y;
  float pos = (float)positions[t];
  float inv = __expf(-((float)(2 * lane) * (1.0f / HD_)) * LN_THETA);
  float fr = pos * inv;
  float c = cosf(fr), sn = sinf(fr);
  float o1 = y1 * c - y2 * sn;
  float o2 = y2 * c + y1 * sn;
  if (isq) { o1 *= ATT_SCALE; o2 *= ATT_SCALE; }
  *(uint32_t*)(row + lane * 2) =
      (uint32_t)f2bf(o1) | ((uint32_t)f2bf(o2) << 16);
}

// ---------------------------------------------------------------------------
// 5) V transpose: qkv v-part [t][kvh*128+hd] -> Vt[kvh][hd][t] (bf16)
__global__ void vt_kernel(const unsigned short* __restrict__ qkv,
                          unsigned short* __restrict__ vt) {
  __shared__ unsigned short tile[32][33];
  const int kvh = blockIdx.z;
  const int t0 = blockIdx.x * 32, d0 = blockIdx.y * 32;
  const int tx = threadIdx.x, ty = threadIdx.y;   // (32, 8)
  for (int i = 0; i < 32; i += 8)
    tile[ty + i][tx] =
        qkv[(size_t)(t0 + ty + i) * QKV_N + H_DIM + NKV_H * HD_ + kvh * HD_ + d0 + tx];
  __syncthreads();
  for (int i = 0; i < 32; i += 8)
    vt[((size_t)kvh * HD_ + d0 + ty + i) * T_SEQ + t0 + tx] = tile[tx][ty + i];
}

// ---------------------------------------------------------------------------
// 6) Flash attention: block = (64-row Q-tile, head); 4 waves x 16 Q-rows.
//    64-key tiles, QK^T + online softmax + PV all in MFMA 16x16x32 bf16.
//    Load balance: block bx processes qt=bx AND qt=NQT-1-bx, so every block
//    does exactly NQT+1 K-tile steps (causal work is uniform across blocks).
__global__ __launch_bounds__(256) void attn_kernel(
    const unsigned short* __restrict__ qkv, const unsigned short* __restrict__ vt,
    unsigned short* __restrict__ out) {
  __shared__ unsigned short Ks[64 * 136];    // K-tile  [key][hd], pad 128->136
  __shared__ unsigned short Vs[128 * 72];    // Vt-tile [hd][key], pad 64->72
  __shared__ unsigned short Ps[4][16 * 72];  // per-wave P  [qrow][key]
  const int tid = threadIdx.x, lane = tid & 63, wid = tid >> 6;
  const int g = lane >> 4, s = lane & 15;
  const int h = blockIdx.y;
  const int kvh = h >> 2;                    // GQA: 4 q-heads per kv-head
  const int NQT = T_SEQ / 64;

  for (int half = 0; half < 2; half++) {
    const int qt = (half == 0) ? (int)blockIdx.x : NQT - 1 - (int)blockIdx.x;
    const int q0 = qt * 64;

    // Q fragments direct from global (A-layout: m=lane&15, k=(lane>>4)*8+j)
    bf16x8 qf[4];
    {
      const unsigned short* qrow =
          qkv + (size_t)(q0 + wid * 16 + s) * QKV_N + h * HD_;
      for (int ks = 0; ks < 4; ks++)
        qf[ks] = *(const bf16x8*)(qrow + ks * 32 + g * 8);
    }
    f32x4 o[8] = {};
    float m_i[4], l_i[4];
    for (int r = 0; r < 4; r++) { m_i[r] = -1e30f; l_i[r] = 0.f; }

    const int ktiles = qt + 1;
    for (int kt = 0; kt < ktiles; kt++) {
      const int k0 = kt * 64;
      __syncthreads();   // previous iter's PV reads of Ks/Vs done
      {
        int kr = tid >> 4, kc = tid & 15;      // K: 16 lanes/row x 16B
        for (int p = 0; p < 4; p++) {
          bf16x8 v = *(const bf16x8*)(qkv + (size_t)(k0 + kr + p * 16) * QKV_N +
                                      H_DIM + kvh * HD_ + kc * 8);
          *(bf16x8*)&Ks[(kr + p * 16) * 136 + kc * 8] = v;
        }
        int vr = tid >> 3, vc = tid & 7;       // Vt: 8 lanes/row x 16B
        for (int p = 0; p < 4; p++) {
          bf16x8 v = *(const bf16x8*)(vt + ((size_t)kvh * HD_ + vr + p * 32) * T_SEQ +
                                      k0 + vc * 8);
          *(bf16x8*)&Vs[(vr + p * 32) * 72 + vc * 8] = v;
        }
      }
      __syncthreads();
      // S = Q*K^T  (4 key-subtiles x 4 k-steps)
      f32x4 sa[4] = {};
      for (int nt = 0; nt < 4; nt++)
        for (int ks = 0; ks < 4; ks++) {
          bf16x8 kb = *(const bf16x8*)&Ks[(nt * 16 + s) * 136 + ks * 32 + g * 8];
          sa[nt] = __builtin_amdgcn_mfma_f32_16x16x32_bf16(qf[ks], kb, sa[nt], 0, 0, 0);
        }
      if (kt == ktiles - 1) {   // causal mask only ever clips the diagonal tile
        for (int nt = 0; nt < 4; nt++)
          for (int r = 0; r < 4; r++)
            if (k0 + nt * 16 + s > q0 + wid * 16 + g * 4 + r) sa[nt][r] = -1e30f;
      }
      // online softmax (rows live across the 16 lanes of each quad-group)
      float alpha[4];
      for (int r = 0; r < 4; r++) {
        float mx = fmaxf(fmaxf(sa[0][r], sa[1][r]), fmaxf(sa[2][r], sa[3][r]));
        for (int off = 1; off < 16; off <<= 1) mx = fmaxf(mx, __shfl_xor(mx, off, 64));
        float mn = fmaxf(m_i[r], mx);
        alpha[r] = __expf(m_i[r] - mn);
        m_i[r] = mn;
        float rsum = 0.f;
        for (int nt = 0; nt < 4; nt++) {
          float p = __expf(sa[nt][r] - mn);
          sa[nt][r] = p;
          rsum += p;
        }
        for (int off = 1; off < 16; off <<= 1) rsum += __shfl_xor(rsum, off, 64);
        l_i[r] = l_i[r] * alpha[r] + rsum;
      }
      for (int nt = 0; nt < 4; nt++)          // P -> LDS (C-layout -> A-layout)
        for (int r = 0; r < 4; r++)
          Ps[wid][(g * 4 + r) * 72 + nt * 16 + s] = f2bf(sa[nt][r]);
      for (int ot = 0; ot < 8; ot++)
        for (int r = 0; r < 4; r++) o[ot][r] *= alpha[r];
      __syncthreads();   // Ps visible (and orders same-wave LDS RAW)
      // O += P*V
      for (int ot = 0; ot < 8; ot++)
        for (int ks = 0; ks < 2; ks++) {
          bf16x8 pa = *(const bf16x8*)&Ps[wid][s * 72 + ks * 32 + g * 8];
          bf16x8 vb = *(const bf16x8*)&Vs[(ot * 16 + s) * 72 + ks * 32 + g * 8];
          o[ot] = __builtin_amdgcn_mfma_f32_16x16x32_bf16(pa, vb, o[ot], 0, 0, 0);
        }
    }
    const size_t obase = (size_t)(q0 + wid * 16);
    for (int ot = 0; ot < 8; ot++)
      for (int r = 0; r < 4; r++) {
        float v = o[ot][r] / l_i[r];
        out[(obase + g * 4 + r) * (size_t)(NH_Q * HD_) + h * HD_ + ot * 16 + s] =
            f2bf(v);
      }
  }
}

// ---------------------------------------------------------------------------
extern "C" void kernel_launch(void* const* d_in, const int* in_sizes, int n_in,
                              void* d_out, int out_size, void* d_ws, size_t ws_size,
                              hipStream_t stream) {
  const int*   positions = (const int*)d_in[0];
  const float* hs        = (const float*)d_in[1];
  const float* w_qkv     = (const float*)d_in[2];
  const float* w_o       = (const float*)d_in[3];
  const float* q_norm_w  = (const float*)d_in[4];
  const float* k_norm_w  = (const float*)d_in[5];
  float* out = (float*)d_out;

  // workspace carve-up (total ~140 MiB)
  char* p = (char*)d_ws;
  unsigned short* hsb   = (unsigned short*)p; p += (size_t)T_SEQ * H_DIM * 2;      // 16M
  unsigned short* wqkvT = (unsigned short*)p; p += (size_t)QKV_N * H_DIM * 2;      // 48M
  unsigned short* woT   = (unsigned short*)p; p += (size_t)H_DIM * H_DIM * 2;      // 32M
  unsigned short* qkvb  = (unsigned short*)p; p += (size_t)T_SEQ * QKV_N * 2;      // 24M
  unsigned short* attnb = (unsigned short*)p; p += (size_t)T_SEQ * H_DIM * 2;      // 16M
  unsigned short* vtb   = (unsigned short*)p; p += (size_t)NKV_H * HD_ * T_SEQ * 2; // 4M

  // 1) converts / transposes
  convert_bf16_kernel<<<(T_SEQ * H_DIM / 4 + 255) / 256, 256, 0, stream>>>(
      hs, hsb, T_SEQ * H_DIM / 4);
  transpose_bf16_kernel<<<dim3(QKV_N / 32, H_DIM / 32), dim3(32, 8), 0, stream>>>(
      w_qkv, wqkvT, H_DIM, QKV_N);
  transpose_bf16_kernel<<<dim3(H_DIM / 32, H_DIM / 32), dim3(32, 8), 0, stream>>>(
      w_o, woT, H_DIM, H_DIM);
  // 2) QKV projection
  gemm_bt_kernel<true><<<dim3(QKV_N / 128, T_SEQ / 128), 256, 0, stream>>>(
      hsb, wqkvT, qkvb, T_SEQ, QKV_N, H_DIM);
  // 3) LN + RoPE (in place; q also scaled by 1/sqrt(HD))
  ln_rope_kernel<<<T_SEQ * (NH_Q + NKV_H) / 4, 256, 0, stream>>>(
      qkvb, positions, q_norm_w, k_norm_w);
  // 4) V transpose for PV B-operand
  vt_kernel<<<dim3(T_SEQ / 32, HD_ / 32, NKV_H), dim3(32, 8), 0, stream>>>(qkvb, vtb);
  // 5) flash attention (paired Q-tiles: uniform work per block)
  attn_kernel<<<dim3(T_SEQ / 128, NH_Q), 256, 0, stream>>>(qkvb, vtb, attnb);
  // 6) output projection
  gemm_bt_kernel<false><<<dim3(H_DIM / 128, T_SEQ / 128), 256, 0, stream>>>(
      attnb, woT, out, T_SEQ, H_DIM, H_DIM);
}

// Round 2
// 600.470 us; speedup vs baseline: 1.1801x; 1.0036x over previous
//
#include <hip/hip_runtime.h>
#include <cstdint>
#include <cstddef>

// Problem constants (CohereAttention: T=2048, H=4096, NH=32, NKV=8, HD=128)
#define T_SEQ   2048
#define H_DIM   4096
#define NH_Q    32
#define NKV_H   8
#define HD_     128
#define QKV_N   6144            // (NH + 2*NKV) * HD
#define EPS_F   1e-5f
#define ATT_SCALE 0.08838834764831845f   // 1/sqrt(128)
#define LN_THETA  9.210340371976184f     // ln(10000)

typedef __attribute__((ext_vector_type(8))) short bf16x8;
typedef __attribute__((ext_vector_type(4))) float f32x4;

static __device__ __forceinline__ unsigned short f2bf(float f) {
  union { float f; uint32_t u; } v; v.f = f;
  uint32_t u = v.u;
  u += 0x7fff + ((u >> 16) & 1);        // RNE
  return (unsigned short)(u >> 16);
}
static __device__ __forceinline__ float bf2f(unsigned short h) {
  union { uint32_t u; float f; } v; v.u = ((uint32_t)h) << 16;
  return v.f;
}

// async global->LDS, 16B per lane; LDS dest is wave-uniform base + lane*16
static __device__ __forceinline__ void gld_lds16(const void* g, void* l) {
  __builtin_amdgcn_global_load_lds(
      (const __attribute__((address_space(1))) unsigned int*)g,
      (__attribute__((address_space(3))) unsigned int*)l, 16, 0, 0);
}

// ---------------------------------------------------------------------------
// 1) fp32 -> bf16 elementwise convert (hidden_states)
__global__ void convert_bf16_kernel(const float* __restrict__ in,
                                    unsigned short* __restrict__ out, int n4) {
  int i = blockIdx.x * blockDim.x + threadIdx.x;
  if (i < n4) {
    float4 f = *(const float4*)(in + (size_t)i * 4);
    ushort4 o;
    o.x = f2bf(f.x); o.y = f2bf(f.y); o.z = f2bf(f.z); o.w = f2bf(f.w);
    *(ushort4*)(out + (size_t)i * 4) = o;
  }
}

// ---------------------------------------------------------------------------
// 2) fp32 [R][C] -> bf16 [C][R] transpose-convert (weights -> Bt layout)
__global__ void transpose_bf16_kernel(const float* __restrict__ in,
                                      unsigned short* __restrict__ out,
                                      int R, int C) {
  __shared__ float tile[32][33];
  int c0 = blockIdx.x * 32, r0 = blockIdx.y * 32;
  int tx = threadIdx.x, ty = threadIdx.y;   // blockDim = (32, 8)
  for (int i = 0; i < 32; i += 8)
    tile[ty + i][tx] = in[(size_t)(r0 + ty + i) * C + c0 + tx];
  __syncthreads();
  for (int i = 0; i < 32; i += 8)
    out[(size_t)(c0 + ty + i) * R + r0 + tx] = f2bf(tile[tx][ty + i]);
}

// ---------------------------------------------------------------------------
// 3) GEMM 256x256 tile, BK=64, 8 waves (2M x 4N), 8-phase counted-vmcnt
//    schedule (T2 swizzle + T3/T4 pipeline + T5 setprio).
//    A bf16 row-major [M][K]; Bt = B^T bf16 [N][K]. M,N % 256 == 0, K % 128 == 0.
//
//    LDS: double-buffered As/Bs [256][64] bf16 (128 KiB total), written
//    linearly by global_load_lds; bank-conflict-free via chunk ^= (row&7)
//    applied to the per-lane GLOBAL source address (write side) and to the
//    ds_read address (read side).
//
//    Staging schedule per K-tile t (4 phases):
//      ph0: stage A(t+1) half0 -> nxt   (A(t-1) fully consumed by now)
//      ph1: stage A(t+1) half1 -> nxt
//      ph2: stage B(t+2) half0 -> cur   (B(t) consumed in ph0)
//      ph3: stage B(t+2) half1 -> cur, then s_waitcnt vmcnt(4): everything
//           except B(t+2) has landed; B(t+2)'s 4 loads stay in flight
//           across the end-of-tile barrier (never drain to 0 mid-loop).
template <bool BF16OUT>
__global__ __launch_bounds__(512, 2) void gemm256_kernel(
    const unsigned short* __restrict__ A, const unsigned short* __restrict__ Bt,
    void* __restrict__ Cp, int M, int N, int K) {
  __shared__ unsigned short As[2][256 * 64];
  __shared__ unsigned short Bs[2][256 * 64];
  const int tid = threadIdx.x, lane = tid & 63, wid = tid >> 6;
  const int wm = wid >> 2, wn = wid & 3;        // 2M x 4N wave grid
  const int g = lane >> 4, s = lane & 15, s7 = s & 7;
  const int m0 = blockIdx.y * 256, n0 = blockIdx.x * 256;
  const int NT = K >> 6;

  // staging: each wave covers 16 rows/half-tile, 2 x gld_lds16 (8 rows each).
  // lane l -> row lr = l>>3, chunk lc = l&7; source pre-swizzled: lc ^ lr.
  const int lr = lane >> 3, lc = lane & 7;
  const size_t src_lane = (size_t)lr * K + (size_t)((lc ^ lr) * 8);

  auto stage_half = [&](const unsigned short* grow, unsigned short* lhalf) {
    gld_lds16(grow + (size_t)(wid * 16) * K + src_lane, lhalf + wid * 1024);
    gld_lds16(grow + (size_t)(wid * 16 + 8) * K + src_lane,
              lhalf + wid * 1024 + 512);
  };

  // ds_read offsets (elements). frag(fr/fc, ks) at row base + fr*16 + s,
  // chunk (ks*4+g) ^ (row&7); row&7 == s7 since all bases are %8 == 0.
  const int aroff = (wm * 128 + s) * 64;
  const int broff = (wn * 64 + s) * 64;
  const int ck0 = ((0 * 4 + g) ^ s7) * 8;
  const int ck1 = ((1 * 4 + g) ^ s7) * 8;

  f32x4 acc[8][4] = {};

  // ---- prologue: A(0), B(0), B(1); wait for tile0 (B(1) stays in flight)
  stage_half(A  + (size_t)(m0)       * K, &As[0][0]);
  stage_half(A  + (size_t)(m0 + 128) * K, &As[0][128 * 64]);
  stage_half(Bt + (size_t)(n0)       * K, &Bs[0][0]);
  stage_half(Bt + (size_t)(n0 + 128) * K, &Bs[0][128 * 64]);
  stage_half(Bt + (size_t)(n0)       * K + 64, &Bs[1][0]);
  stage_half(Bt + (size_t)(n0 + 128) * K + 64, &Bs[1][128 * 64]);
  asm volatile("s_waitcnt vmcnt(4)" ::: "memory");
  __builtin_amdgcn_s_barrier();

  auto tile_step = [&](unsigned short* cA, unsigned short* cB,
                       unsigned short* nA, int t) {
    const int k0 = t << 6;
    // B fragments for the whole K-tile (8 x ds_read_b128), read in phase 0
    bf16x8 bfr[4][2];
#pragma unroll
    for (int fc = 0; fc < 4; fc++) {
      bfr[fc][0] = *(const bf16x8*)(cB + broff + fc * 1024 + ck0);
      bfr[fc][1] = *(const bf16x8*)(cB + broff + fc * 1024 + ck1);
    }
#pragma unroll
    for (int ph = 0; ph < 4; ph++) {
      bf16x8 a[2][2];
#pragma unroll
      for (int i = 0; i < 2; i++) {
        const int fr = ph * 2 + i;
        a[i][0] = *(const bf16x8*)(cA + aroff + fr * 1024 + ck0);
        a[i][1] = *(const bf16x8*)(cA + aroff + fr * 1024 + ck1);
      }
      if (ph == 0 && t + 1 < NT)
        stage_half(A + (size_t)(m0) * K + k0 + 64, nA);
      if (ph == 1 && t + 1 < NT)
        stage_half(A + (size_t)(m0 + 128) * K + k0 + 64, nA + 128 * 64);
      if (ph == 2 && t + 2 < NT)
        stage_half(Bt + (size_t)(n0) * K + k0 + 128, cB);
      if (ph == 3 && t + 2 < NT)
        stage_half(Bt + (size_t)(n0 + 128) * K + k0 + 128, cB + 128 * 64);
      __builtin_amdgcn_s_barrier();
      asm volatile("s_waitcnt lgkmcnt(0)" ::: "memory");
      __builtin_amdgcn_sched_barrier(0);
      __builtin_amdgcn_s_setprio(1);
#pragma unroll
      for (int i = 0; i < 2; i++) {
        const int fr = ph * 2 + i;
#pragma unroll
        for (int fc = 0; fc < 4; fc++) {
          acc[fr][fc] = __builtin_amdgcn_mfma_f32_16x16x32_bf16(
              a[i][0], bfr[fc][0], acc[fr][fc], 0, 0, 0);
          acc[fr][fc] = __builtin_amdgcn_mfma_f32_16x16x32_bf16(
              a[i][1], bfr[fc][1], acc[fr][fc], 0, 0, 0);
        }
      }
      __builtin_amdgcn_s_setprio(0);
      __builtin_amdgcn_sched_barrier(0);
      if (ph == 3) {
        if (t + 2 < NT) asm volatile("s_waitcnt vmcnt(4)" ::: "memory");
        else            asm volatile("s_waitcnt vmcnt(0)" ::: "memory");
      }
      __builtin_amdgcn_s_barrier();
    }
  };

  for (int t = 0; t < NT; t += 2) {
    tile_step(&As[0][0], &Bs[0][0], &As[1][0], t);
    tile_step(&As[1][0], &Bs[1][0], &As[0][0], t + 1);
  }

  // ---- epilogue: C/D layout row = g*4 + r, col = s (per 16x16 fragment)
#pragma unroll
  for (int fr = 0; fr < 8; fr++)
#pragma unroll
    for (int fc = 0; fc < 4; fc++)
#pragma unroll
      for (int r = 0; r < 4; r++) {
        int m = m0 + wm * 128 + fr * 16 + g * 4 + r;
        int n = n0 + wn * 64 + fc * 16 + s;
        float v = acc[fr][fc][r];
        if (BF16OUT) ((unsigned short*)Cp)[(size_t)m * N + n] = f2bf(v);
        else         ((float*)Cp)[(size_t)m * N + n] = v;
      }
}

// ---------------------------------------------------------------------------
// 4) Per-(t,head) LayerNorm + interleaved RoPE, in-place on qkv buffer.
__global__ __launch_bounds__(256) void ln_rope_kernel(
    unsigned short* __restrict__ qkv, const int* __restrict__ positions,
    const float* __restrict__ qw, const float* __restrict__ kw) {
  const int wid = threadIdx.x >> 6, lane = threadIdx.x & 63;
  const int rid = blockIdx.x * 4 + wid;     // 0 .. T*(NH+NKV)-1
  const int t = rid / 40, hh = rid % 40;
  const bool isq = hh < NH_Q;
  const int col = isq ? hh * HD_ : H_DIM + (hh - NH_Q) * HD_;
  unsigned short* row = qkv + (size_t)t * QKV_N + col;

  uint32_t both = *(const uint32_t*)(row + lane * 2);
  float x1 = bf2f((unsigned short)(both & 0xffff));
  float x2 = bf2f((unsigned short)(both >> 16));
  float ssum = x1 + x2, ssq = x1 * x1 + x2 * x2;
  for (int off = 1; off < 64; off <<= 1) {
    ssum += __shfl_xor(ssum, off, 64);
    ssq  += __shfl_xor(ssq,  off, 64);
  }
  float mean = ssum * (1.0f / HD_);
  float var  = ssq * (1.0f / HD_) - mean * mean;
  float rs = rsqrtf(var + EPS_F);
  const float* w = isq ? (qw + hh * HD_) : (kw + (hh - NH_Q) * HD_);
  float2 wv = *(const float2*)(w + lane * 2);
  float y1 = (x1 - mean) * rs * wv.x;
  float y2 = (x2 - mean) * rs * wv.y;
  float pos = (float)positions[t];
  float inv = __expf(-((float)(2 * lane) * (1.0f / HD_)) * LN_THETA);
  float fr = pos * inv;
  float c = cosf(fr), sn = sinf(fr);
  float o1 = y1 * c - y2 * sn;
  float o2 = y2 * c + y1 * sn;
  if (isq) { o1 *= ATT_SCALE; o2 *= ATT_SCALE; }
  *(uint32_t*)(row + lane * 2) =
      (uint32_t)f2bf(o1) | ((uint32_t)f2bf(o2) << 16);
}

// ---------------------------------------------------------------------------
// 5) V transpose: qkv v-part [t][kvh*128+hd] -> Vt[kvh][hd][t] (bf16)
__global__ void vt_kernel(const unsigned short* __restrict__ qkv,
                          unsigned short* __restrict__ vt) {
  __shared__ unsigned short tile[32][33];
  const int kvh = blockIdx.z;
  const int t0 = blockIdx.x * 32, d0 = blockIdx.y * 32;
  const int tx = threadIdx.x, ty = threadIdx.y;   // (32, 8)
  for (int i = 0; i < 32; i += 8)
    tile[ty + i][tx] =
        qkv[(size_t)(t0 + ty + i) * QKV_N + H_DIM + NKV_H * HD_ + kvh * HD_ + d0 + tx];
  __syncthreads();
  for (int i = 0; i < 32; i += 8)
    vt[((size_t)kvh * HD_ + d0 + ty + i) * T_SEQ + t0 + tx] = tile[tx][ty + i];
}

// ---------------------------------------------------------------------------
// 6) Flash attention: block = (64-row Q-tile, head); 4 waves x 16 Q-rows.
//    Load balance: block bx processes qt=bx AND qt=NQT-1-bx (uniform work).
__global__ __launch_bounds__(256) void attn_kernel(
    const unsigned short* __restrict__ qkv, const unsigned short* __restrict__ vt,
    unsigned short* __restrict__ out) {
  __shared__ unsigned short Ks[64 * 136];    // K-tile  [key][hd], pad 128->136
  __shared__ unsigned short Vs[128 * 72];    // Vt-tile [hd][key], pad 64->72
  __shared__ unsigned short Ps[4][16 * 72];  // per-wave P  [qrow][key]
  const int tid = threadIdx.x, lane = tid & 63, wid = tid >> 6;
  const int g = lane >> 4, s = lane & 15;
  const int h = blockIdx.y;
  const int kvh = h >> 2;                    // GQA: 4 q-heads per kv-head
  const int NQT = T_SEQ / 64;

  for (int half = 0; half < 2; half++) {
    const int qt = (half == 0) ? (int)blockIdx.x : NQT - 1 - (int)blockIdx.x;
    const int q0 = qt * 64;

    bf16x8 qf[4];
    {
      const unsigned short* qrow =
          qkv + (size_t)(q0 + wid * 16 + s) * QKV_N + h * HD_;
      for (int ks = 0; ks < 4; ks++)
        qf[ks] = *(const bf16x8*)(qrow + ks * 32 + g * 8);
    }
    f32x4 o[8] = {};
    float m_i[4], l_i[4];
    for (int r = 0; r < 4; r++) { m_i[r] = -1e30f; l_i[r] = 0.f; }

    const int ktiles = qt + 1;
    for (int kt = 0; kt < ktiles; kt++) {
      const int k0 = kt * 64;
      __syncthreads();   // previous iter's PV reads of Ks/Vs done
      {
        int kr = tid >> 4, kc = tid & 15;      // K: 16 lanes/row x 16B
        for (int p = 0; p < 4; p++) {
          bf16x8 v = *(const bf16x8*)(qkv + (size_t)(k0 + kr + p * 16) * QKV_N +
                                      H_DIM + kvh * HD_ + kc * 8);
          *(bf16x8*)&Ks[(kr + p * 16) * 136 + kc * 8] = v;
        }
        int vr = tid >> 3, vc = tid & 7;       // Vt: 8 lanes/row x 16B
        for (int p = 0; p < 4; p++) {
          bf16x8 v = *(const bf16x8*)(vt + ((size_t)kvh * HD_ + vr + p * 32) * T_SEQ +
                                      k0 + vc * 8);
          *(bf16x8*)&Vs[(vr + p * 32) * 72 + vc * 8] = v;
        }
      }
      __syncthreads();
      f32x4 sa[4] = {};
      for (int nt = 0; nt < 4; nt++)
        for (int ks = 0; ks < 4; ks++) {
          bf16x8 kb = *(const bf16x8*)&Ks[(nt * 16 + s) * 136 + ks * 32 + g * 8];
          sa[nt] = __builtin_amdgcn_mfma_f32_16x16x32_bf16(qf[ks], kb, sa[nt], 0, 0, 0);
        }
      if (kt == ktiles - 1) {   // causal mask only ever clips the diagonal tile
        for (int nt = 0; nt < 4; nt++)
          for (int r = 0; r < 4; r++)
            if (k0 + nt * 16 + s > q0 + wid * 16 + g * 4 + r) sa[nt][r] = -1e30f;
      }
      float alpha[4];
      for (int r = 0; r < 4; r++) {
        float mx = fmaxf(fmaxf(sa[0][r], sa[1][r]), fmaxf(sa[2][r], sa[3][r]));
        for (int off = 1; off < 16; off <<= 1) mx = fmaxf(mx, __shfl_xor(mx, off, 64));
        float mn = fmaxf(m_i[r], mx);
        alpha[r] = __expf(m_i[r] - mn);
        m_i[r] = mn;
        float rsum = 0.f;
        for (int nt = 0; nt < 4; nt++) {
          float p = __expf(sa[nt][r] - mn);
          sa[nt][r] = p;
          rsum += p;
        }
        for (int off = 1; off < 16; off <<= 1) rsum += __shfl_xor(rsum, off, 64);
        l_i[r] = l_i[r] * alpha[r] + rsum;
      }
      for (int nt = 0; nt < 4; nt++)          // P -> LDS (C-layout -> A-layout)
        for (int r = 0; r < 4; r++)
          Ps[wid][(g * 4 + r) * 72 + nt * 16 + s] = f2bf(sa[nt][r]);
      for (int ot = 0; ot < 8; ot++)
        for (int r = 0; r < 4; r++) o[ot][r] *= alpha[r];
      __syncthreads();   // Ps visible (and orders same-wave LDS RAW)
      for (int ot = 0; ot < 8; ot++)
        for (int ks = 0; ks < 2; ks++) {
          bf16x8 pa = *(const bf16x8*)&Ps[wid][s * 72 + ks * 32 + g * 8];
          bf16x8 vb = *(const bf16x8*)&Vs[(ot * 16 + s) * 72 + ks * 32 + g * 8];
          o[ot] = __builtin_amdgcn_mfma_f32_16x16x32_bf16(pa, vb, o[ot], 0, 0, 0);
        }
    }
    const size_t obase = (size_t)(q0 + wid * 16);
    for (int ot = 0; ot < 8; ot++)
      for (int r = 0; r < 4; r++) {
        float v = o[ot][r] / l_i[r];
        out[(obase + g * 4 + r) * (size_t)(NH_Q * HD_) + h * HD_ + ot * 16 + s] =
            f2bf(v);
      }
  }
}

// ---------------------------------------------------------------------------
extern "C" void kernel_launch(void* const* d_in, const int* in_sizes, int n_in,
                              void* d_out, int out_size, void* d_ws, size_t ws_size,
                              hipStream_t stream) {
  const int*   positions = (const int*)d_in[0];
  const float* hs        = (const float*)d_in[1];
  const float* w_qkv     = (const float*)d_in[2];
  const float* w_o       = (const float*)d_in[3];
  const float* q_norm_w  = (const float*)d_in[4];
  const float* k_norm_w  = (const float*)d_in[5];
  float* out = (float*)d_out;

  // workspace carve-up (total ~140 MiB)
  char* p = (char*)d_ws;
  unsigned short* hsb   = (unsigned short*)p; p += (size_t)T_SEQ * H_DIM * 2;      // 16M
  unsigned short* wqkvT = (unsigned short*)p; p += (size_t)QKV_N * H_DIM * 2;      // 48M
  unsigned short* woT   = (unsigned short*)p; p += (size_t)H_DIM * H_DIM * 2;      // 32M
  unsigned short* qkvb  = (unsigned short*)p; p += (size_t)T_SEQ * QKV_N * 2;      // 24M
  unsigned short* attnb = (unsigned short*)p; p += (size_t)T_SEQ * H_DIM * 2;      // 16M
  unsigned short* vtb   = (unsigned short*)p; p += (size_t)NKV_H * HD_ * T_SEQ * 2; // 4M

  // 1) converts / transposes
  convert_bf16_kernel<<<(T_SEQ * H_DIM / 4 + 255) / 256, 256, 0, stream>>>(
      hs, hsb, T_SEQ * H_DIM / 4);
  transpose_bf16_kernel<<<dim3(QKV_N / 32, H_DIM / 32), dim3(32, 8), 0, stream>>>(
      w_qkv, wqkvT, H_DIM, QKV_N);
  transpose_bf16_kernel<<<dim3(H_DIM / 32, H_DIM / 32), dim3(32, 8), 0, stream>>>(
      w_o, woT, H_DIM, H_DIM);
  // 2) QKV projection (256^2 8-phase)
  gemm256_kernel<true><<<dim3(QKV_N / 256, T_SEQ / 256), 512, 0, stream>>>(
      hsb, wqkvT, qkvb, T_SEQ, QKV_N, H_DIM);
  // 3) LN + RoPE (in place; q also scaled by 1/sqrt(HD))
  ln_rope_kernel<<<T_SEQ * (NH_Q + NKV_H) / 4, 256, 0, stream>>>(
      qkvb, positions, q_norm_w, k_norm_w);
  // 4) V transpose for PV B-operand
  vt_kernel<<<dim3(T_SEQ / 32, HD_ / 32, NKV_H), dim3(32, 8), 0, stream>>>(qkvb, vtb);
  // 5) flash attention (paired Q-tiles: uniform work per block)
  attn_kernel<<<dim3(T_SEQ / 128, NH_Q), 256, 0, stream>>>(qkvb, vtb, attnb);
  // 6) output projection (256^2 8-phase)
  gemm256_kernel<false><<<dim3(H_DIM / 256, T_SEQ / 256), 512, 0, stream>>>(
      attnb, woT, out, T_SEQ, H_DIM, H_DIM);
}

// Round 3
// 565.993 us; speedup vs baseline: 1.2520x; 1.0609x over previous
//
#include <hip/hip_runtime.h>
#include <cstdint>
#include <cstddef>

// Problem constants (CohereAttention: T=2048, H=4096, NH=32, NKV=8, HD=128)
#define T_SEQ   2048
#define H_DIM   4096
#define NH_Q    32
#define NKV_H   8
#define HD_     128
#define QKV_N   6144            // (NH + 2*NKV) * HD
#define EPS_F   1e-5f
#define ATT_SCALE 0.08838834764831845f   // 1/sqrt(128)
#define LN_THETA  9.210340371976184f     // ln(10000)

typedef __attribute__((ext_vector_type(8))) short bf16x8;
typedef __attribute__((ext_vector_type(4))) float f32x4;

static __device__ __forceinline__ unsigned short f2bf(float f) {
  union { float f; uint32_t u; } v; v.f = f;
  uint32_t u = v.u;
  u += 0x7fff + ((u >> 16) & 1);        // RNE
  return (unsigned short)(u >> 16);
}
static __device__ __forceinline__ float bf2f(unsigned short h) {
  union { uint32_t u; float f; } v; v.u = ((uint32_t)h) << 16;
  return v.f;
}

// async global->LDS, 16B per lane; LDS dest is wave-uniform base + lane*16
static __device__ __forceinline__ void gld_lds16(const void* g, void* l) {
  __builtin_amdgcn_global_load_lds(
      (const __attribute__((address_space(1))) unsigned int*)g,
      (__attribute__((address_space(3))) unsigned int*)l, 16, 0, 0);
}

// ---------------------------------------------------------------------------
// 1) fp32 -> bf16 elementwise convert (hidden_states)
__global__ void convert_bf16_kernel(const float* __restrict__ in,
                                    unsigned short* __restrict__ out, int n4) {
  int i = blockIdx.x * blockDim.x + threadIdx.x;
  if (i < n4) {
    float4 f = *(const float4*)(in + (size_t)i * 4);
    ushort4 o;
    o.x = f2bf(f.x); o.y = f2bf(f.y); o.z = f2bf(f.z); o.w = f2bf(f.w);
    *(ushort4*)(out + (size_t)i * 4) = o;
  }
}

// ---------------------------------------------------------------------------
// 2) fp32 [R][C] -> bf16 [C][R] transpose-convert (weights -> Bt layout)
__global__ void transpose_bf16_kernel(const float* __restrict__ in,
                                      unsigned short* __restrict__ out,
                                      int R, int C) {
  __shared__ float tile[32][33];
  int c0 = blockIdx.x * 32, r0 = blockIdx.y * 32;
  int tx = threadIdx.x, ty = threadIdx.y;   // blockDim = (32, 8)
  for (int i = 0; i < 32; i += 8)
    tile[ty + i][tx] = in[(size_t)(r0 + ty + i) * C + c0 + tx];
  __syncthreads();
  for (int i = 0; i < 32; i += 8)
    out[(size_t)(c0 + ty + i) * R + r0 + tx] = f2bf(tile[tx][ty + i]);
}

// ---------------------------------------------------------------------------
// 3) GEMM, BM=256, BN=FC*64, BK=64, 8 waves (2M x 4N), phase-pipelined with
//    counted vmcnt (T2 swizzle + T3/T4 + T5). No sched_barrier / forced
//    lgkmcnt(0): the compiler's counted lgkm waits + MFMA interleave are
//    better (m141 lesson). A bf16 row-major [M][K]; Bt = B^T bf16 [N][K].
//    FC=3 -> BN=192 (QKV grid 32x8=256 blocks); FC=2 -> BN=128, PHASES=2
//    (O-proj grid 32x8=256 blocks). Full CU coverage for both.
template <int FC, int PHASES, bool BF16OUT>
__global__ __launch_bounds__(512) void gemm256_kernel(
    const unsigned short* __restrict__ A, const unsigned short* __restrict__ Bt,
    void* __restrict__ Cp, int M, int N, int K) {
  constexpr int BN = FC * 64;
  constexpr int FR_PER = 8 / PHASES;        // fr-rows per phase
  __shared__ unsigned short As[2][256 * 64];
  __shared__ unsigned short Bs[2][BN * 64];
  const int tid = threadIdx.x, lane = tid & 63, wid = tid >> 6;
  const int wm = wid >> 2, wn = wid & 3;    // 2M x 4N wave grid
  const int g = lane >> 4, s = lane & 15, s7 = s & 7;
  const int m0 = blockIdx.y * 256, n0 = blockIdx.x * BN;
  const int NT = K >> 6;

  // staging: lane l -> row lr = l>>3, chunk lc = l&7; source pre-swizzled
  // (lc ^ lr) so a LINEAR gld_lds dest yields the swizzled LDS layout.
  const int lr = lane >> 3, lc = lane & 7;
  const size_t srcoff = (size_t)lr * K + (size_t)((lc ^ lr) * 8);

  // A: wave covers rows wid*32 + h*16 + {0,8}; all bases % 8 == 0
  auto stage_A_half = [&](const unsigned short* gbase, unsigned short* dst,
                          int h) {
    const int r0 = wid * 32 + h * 16;
    gld_lds16(gbase + (size_t)r0 * K + srcoff, dst + r0 * 64);
    gld_lds16(gbase + (size_t)(r0 + 8) * K + srcoff, dst + (r0 + 8) * 64);
  };
  // B: wave covers rows wid*FC*8 + j*8, j<FC
  auto stage_B = [&](const unsigned short* gbase, unsigned short* dst) {
#pragma unroll
    for (int j = 0; j < FC; j++) {
      const int r0 = wid * (FC * 8) + j * 8;
      gld_lds16(gbase + (size_t)r0 * K + srcoff, dst + r0 * 64);
    }
  };

  // ds_read offsets (elements): frag at row base + fr*16 + s,
  // chunk (k2*4+g) ^ (row&7); row&7 == s7 (all bases % 16 == 0).
  const int aroff = (wm * 128 + s) * 64;
  const int broff = (wn * FC * 16 + s) * 64;
  const int ck0 = ((0 * 4 + g) ^ s7) * 8;
  const int ck1 = ((1 * 4 + g) ^ s7) * 8;

  f32x4 acc[8][FC] = {};

  // ---- prologue: A(0)->As0, B(0)->Bs0, B(1)->Bs1; B(1) stays in flight
  stage_A_half(A + (size_t)m0 * K, &As[0][0], 0);
  stage_A_half(A + (size_t)m0 * K, &As[0][0], 1);
  stage_B(Bt + (size_t)n0 * K, &Bs[0][0]);
  stage_B(Bt + (size_t)n0 * K + 64, &Bs[1][0]);
  if constexpr (FC == 2) asm volatile("s_waitcnt vmcnt(2)" ::: "memory");
  else                   asm volatile("s_waitcnt vmcnt(3)" ::: "memory");
  __builtin_amdgcn_s_barrier();

  auto tile_step = [&](int t, unsigned short* cA, unsigned short* cB,
                       unsigned short* nA) {
    const int k0 = t << 6;
    bf16x8 bfr[FC][2];
#pragma unroll
    for (int p = 0; p < PHASES; p++) {
      if (p == 0) {
#pragma unroll
        for (int fc = 0; fc < FC; fc++) {
          bfr[fc][0] = *(const bf16x8*)(cB + broff + fc * 1024 + ck0);
          bfr[fc][1] = *(const bf16x8*)(cB + broff + fc * 1024 + ck1);
        }
      }
      bf16x8 a[FR_PER][2];
#pragma unroll
      for (int i = 0; i < FR_PER; i++) {
        const int fr = p * FR_PER + i;
        a[i][0] = *(const bf16x8*)(cA + aroff + fr * 1024 + ck0);
        a[i][1] = *(const bf16x8*)(cA + aroff + fr * 1024 + ck1);
      }
      // stage: A(t+1) halves in the first phase(s); B(t+2) in the last phase
      if (t + 1 < NT) {
        if (PHASES == 2) {
          if (p == 0) {
            stage_A_half(A + (size_t)m0 * K + k0 + 64, nA, 0);
            stage_A_half(A + (size_t)m0 * K + k0 + 64, nA, 1);
          }
        } else {
          if (p == 0) stage_A_half(A + (size_t)m0 * K + k0 + 64, nA, 0);
          if (p == 1) stage_A_half(A + (size_t)m0 * K + k0 + 64, nA, 1);
        }
      }
      if (p == PHASES - 1 && t + 2 < NT)
        stage_B(Bt + (size_t)n0 * K + k0 + 128, cB);
      __builtin_amdgcn_s_barrier();
      __builtin_amdgcn_s_setprio(1);
      // interleaved: all k2=0 MFMAs first, then k2=1 (no dependent pairs)
#pragma unroll
      for (int i = 0; i < FR_PER; i++) {
        const int fr = p * FR_PER + i;
#pragma unroll
        for (int fc = 0; fc < FC; fc++)
          acc[fr][fc] = __builtin_amdgcn_mfma_f32_16x16x32_bf16(
              a[i][0], bfr[fc][0], acc[fr][fc], 0, 0, 0);
      }
#pragma unroll
      for (int i = 0; i < FR_PER; i++) {
        const int fr = p * FR_PER + i;
#pragma unroll
        for (int fc = 0; fc < FC; fc++)
          acc[fr][fc] = __builtin_amdgcn_mfma_f32_16x16x32_bf16(
              a[i][1], bfr[fc][1], acc[fr][fc], 0, 0, 0);
      }
      __builtin_amdgcn_s_setprio(0);
      if (p == PHASES - 1) {
        if (t + 2 < NT) {
          if constexpr (FC == 2) asm volatile("s_waitcnt vmcnt(2)" ::: "memory");
          else                   asm volatile("s_waitcnt vmcnt(3)" ::: "memory");
        } else {
          asm volatile("s_waitcnt vmcnt(0)" ::: "memory");
        }
      }
      __builtin_amdgcn_s_barrier();
    }
  };

  for (int t = 0; t < NT; t += 2) {
    tile_step(t,     &As[0][0], &Bs[0][0], &As[1][0]);
    tile_step(t + 1, &As[1][0], &Bs[1][0], &As[0][0]);
  }

  // ---- epilogue: C/D layout row = g*4 + r, col = s (per 16x16 fragment)
#pragma unroll
  for (int fr = 0; fr < 8; fr++)
#pragma unroll
    for (int fc = 0; fc < FC; fc++)
#pragma unroll
      for (int r = 0; r < 4; r++) {
        int m = m0 + wm * 128 + fr * 16 + g * 4 + r;
        int n = n0 + wn * FC * 16 + fc * 16 + s;
        float v = acc[fr][fc][r];
        if (BF16OUT) ((unsigned short*)Cp)[(size_t)m * N + n] = f2bf(v);
        else         ((float*)Cp)[(size_t)m * N + n] = v;
      }
}

// ---------------------------------------------------------------------------
// 4) Per-(t,head) LayerNorm + interleaved RoPE, in-place on qkv buffer.
__global__ __launch_bounds__(256) void ln_rope_kernel(
    unsigned short* __restrict__ qkv, const int* __restrict__ positions,
    const float* __restrict__ qw, const float* __restrict__ kw) {
  const int wid = threadIdx.x >> 6, lane = threadIdx.x & 63;
  const int rid = blockIdx.x * 4 + wid;     // 0 .. T*(NH+NKV)-1
  const int t = rid / 40, hh = rid % 40;
  const bool isq = hh < NH_Q;
  const int col = isq ? hh * HD_ : H_DIM + (hh - NH_Q) * HD_;
  unsigned short* row = qkv + (size_t)t * QKV_N + col;

  uint32_t both = *(const uint32_t*)(row + lane * 2);
  float x1 = bf2f((unsigned short)(both & 0xffff));
  float x2 = bf2f((unsigned short)(both >> 16));
  float ssum = x1 + x2, ssq = x1 * x1 + x2 * x2;
  for (int off = 1; off < 64; off <<= 1) {
    ssum += __shfl_xor(ssum, off, 64);
    ssq  += __shfl_xor(ssq,  off, 64);
  }
  float mean = ssum * (1.0f / HD_);
  float var  = ssq * (1.0f / HD_) - mean * mean;
  float rs = rsqrtf(var + EPS_F);
  const float* w = isq ? (qw + hh * HD_) : (kw + (hh - NH_Q) * HD_);
  float2 wv = *(const float2*)(w + lane * 2);
  float y1 = (x1 - mean) * rs * wv.x;
  float y2 = (x2 - mean) * rs * wv.y;
  float pos = (float)positions[t];
  float inv = __expf(-((float)(2 * lane) * (1.0f / HD_)) * LN_THETA);
  float fr = pos * inv;
  float c = cosf(fr), sn = sinf(fr);
  float o1 = y1 * c - y2 * sn;
  float o2 = y2 * c + y1 * sn;
  if (isq) { o1 *= ATT_SCALE; o2 *= ATT_SCALE; }
  *(uint32_t*)(row + lane * 2) =
      (uint32_t)f2bf(o1) | ((uint32_t)f2bf(o2) << 16);
}

// ---------------------------------------------------------------------------
// 5) V transpose: qkv v-part [t][kvh*128+hd] -> Vt[kvh][hd][t] (bf16)
__global__ void vt_kernel(const unsigned short* __restrict__ qkv,
                          unsigned short* __restrict__ vt) {
  __shared__ unsigned short tile[32][33];
  const int kvh = blockIdx.z;
  const int t0 = blockIdx.x * 32, d0 = blockIdx.y * 32;
  const int tx = threadIdx.x, ty = threadIdx.y;   // (32, 8)
  for (int i = 0; i < 32; i += 8)
    tile[ty + i][tx] =
        qkv[(size_t)(t0 + ty + i) * QKV_N + H_DIM + NKV_H * HD_ + kvh * HD_ + d0 + tx];
  __syncthreads();
  for (int i = 0; i < 32; i += 8)
    vt[((size_t)kvh * HD_ + d0 + ty + i) * T_SEQ + t0 + tx] = tile[tx][ty + i];
}

// ---------------------------------------------------------------------------
// 6) Flash attention: block = (64-row Q-tile, head); 4 waves x 16 Q-rows.
//    Load balance: block bx processes qt=bx AND qt=NQT-1-bx (uniform work).
__global__ __launch_bounds__(256) void attn_kernel(
    const unsigned short* __restrict__ qkv, const unsigned short* __restrict__ vt,
    unsigned short* __restrict__ out) {
  __shared__ unsigned short Ks[64 * 136];    // K-tile  [key][hd], pad 128->136
  __shared__ unsigned short Vs[128 * 72];    // Vt-tile [hd][key], pad 64->72
  __shared__ unsigned short Ps[4][16 * 72];  // per-wave P  [qrow][key]
  const int tid = threadIdx.x, lane = tid & 63, wid = tid >> 6;
  const int g = lane >> 4, s = lane & 15;
  const int h = blockIdx.y;
  const int kvh = h >> 2;                    // GQA: 4 q-heads per kv-head
  const int NQT = T_SEQ / 64;

  for (int half = 0; half < 2; half++) {
    const int qt = (half == 0) ? (int)blockIdx.x : NQT - 1 - (int)blockIdx.x;
    const int q0 = qt * 64;

    bf16x8 qf[4];
    {
      const unsigned short* qrow =
          qkv + (size_t)(q0 + wid * 16 + s) * QKV_N + h * HD_;
      for (int ks = 0; ks < 4; ks++)
        qf[ks] = *(const bf16x8*)(qrow + ks * 32 + g * 8);
    }
    f32x4 o[8] = {};
    float m_i[4], l_i[4];
    for (int r = 0; r < 4; r++) { m_i[r] = -1e30f; l_i[r] = 0.f; }

    const int ktiles = qt + 1;
    for (int kt = 0; kt < ktiles; kt++) {
      const int k0 = kt * 64;
      __syncthreads();   // previous iter's PV reads of Ks/Vs done
      {
        int kr = tid >> 4, kc = tid & 15;      // K: 16 lanes/row x 16B
        for (int p = 0; p < 4; p++) {
          bf16x8 v = *(const bf16x8*)(qkv + (size_t)(k0 + kr + p * 16) * QKV_N +
                                      H_DIM + kvh * HD_ + kc * 8);
          *(bf16x8*)&Ks[(kr + p * 16) * 136 + kc * 8] = v;
        }
        int vr = tid >> 3, vc = tid & 7;       // Vt: 8 lanes/row x 16B
        for (int p = 0; p < 4; p++) {
          bf16x8 v = *(const bf16x8*)(vt + ((size_t)kvh * HD_ + vr + p * 32) * T_SEQ +
                                      k0 + vc * 8);
          *(bf16x8*)&Vs[(vr + p * 32) * 72 + vc * 8] = v;
        }
      }
      __syncthreads();
      f32x4 sa[4] = {};
      __builtin_amdgcn_s_setprio(1);
      for (int nt = 0; nt < 4; nt++)
        for (int ks = 0; ks < 4; ks++) {
          bf16x8 kb = *(const bf16x8*)&Ks[(nt * 16 + s) * 136 + ks * 32 + g * 8];
          sa[nt] = __builtin_amdgcn_mfma_f32_16x16x32_bf16(qf[ks], kb, sa[nt], 0, 0, 0);
        }
      __builtin_amdgcn_s_setprio(0);
      if (kt == ktiles - 1) {   // causal mask only ever clips the diagonal tile
        for (int nt = 0; nt < 4; nt++)
          for (int r = 0; r < 4; r++)
            if (k0 + nt * 16 + s > q0 + wid * 16 + g * 4 + r) sa[nt][r] = -1e30f;
      }
      float alpha[4];
      for (int r = 0; r < 4; r++) {
        float mx = fmaxf(fmaxf(sa[0][r], sa[1][r]), fmaxf(sa[2][r], sa[3][r]));
        for (int off = 1; off < 16; off <<= 1) mx = fmaxf(mx, __shfl_xor(mx, off, 64));
        float mn = fmaxf(m_i[r], mx);
        alpha[r] = __expf(m_i[r] - mn);
        m_i[r] = mn;
        float rsum = 0.f;
        for (int nt = 0; nt < 4; nt++) {
          float p = __expf(sa[nt][r] - mn);
          sa[nt][r] = p;
          rsum += p;
        }
        for (int off = 1; off < 16; off <<= 1) rsum += __shfl_xor(rsum, off, 64);
        l_i[r] = l_i[r] * alpha[r] + rsum;
      }
      for (int nt = 0; nt < 4; nt++)          // P -> LDS (C-layout -> A-layout)
        for (int r = 0; r < 4; r++)
          Ps[wid][(g * 4 + r) * 72 + nt * 16 + s] = f2bf(sa[nt][r]);
      for (int ot = 0; ot < 8; ot++)
        for (int r = 0; r < 4; r++) o[ot][r] *= alpha[r];
      __syncthreads();   // Ps visible (and orders same-wave LDS RAW)
      __builtin_amdgcn_s_setprio(1);
      for (int ot = 0; ot < 8; ot++)
        for (int ks = 0; ks < 2; ks++) {
          bf16x8 pa = *(const bf16x8*)&Ps[wid][s * 72 + ks * 32 + g * 8];
          bf16x8 vb = *(const bf16x8*)&Vs[(ot * 16 + s) * 72 + ks * 32 + g * 8];
          o[ot] = __builtin_amdgcn_mfma_f32_16x16x32_bf16(pa, vb, o[ot], 0, 0, 0);
        }
      __builtin_amdgcn_s_setprio(0);
    }
    const size_t obase = (size_t)(q0 + wid * 16);
    for (int ot = 0; ot < 8; ot++)
      for (int r = 0; r < 4; r++) {
        float v = o[ot][r] / l_i[r];
        out[(obase + g * 4 + r) * (size_t)(NH_Q * HD_) + h * HD_ + ot * 16 + s] =
            f2bf(v);
      }
  }
}

// ---------------------------------------------------------------------------
extern "C" void kernel_launch(void* const* d_in, const int* in_sizes, int n_in,
                              void* d_out, int out_size, void* d_ws, size_t ws_size,
                              hipStream_t stream) {
  const int*   positions = (const int*)d_in[0];
  const float* hs        = (const float*)d_in[1];
  const float* w_qkv     = (const float*)d_in[2];
  const float* w_o       = (const float*)d_in[3];
  const float* q_norm_w  = (const float*)d_in[4];
  const float* k_norm_w  = (const float*)d_in[5];
  float* out = (float*)d_out;

  // workspace carve-up (total ~140 MiB)
  char* p = (char*)d_ws;
  unsigned short* hsb   = (unsigned short*)p; p += (size_t)T_SEQ * H_DIM * 2;      // 16M
  unsigned short* wqkvT = (unsigned short*)p; p += (size_t)QKV_N * H_DIM * 2;      // 48M
  unsigned short* woT   = (unsigned short*)p; p += (size_t)H_DIM * H_DIM * 2;      // 32M
  unsigned short* qkvb  = (unsigned short*)p; p += (size_t)T_SEQ * QKV_N * 2;      // 24M
  unsigned short* attnb = (unsigned short*)p; p += (size_t)T_SEQ * H_DIM * 2;      // 16M
  unsigned short* vtb   = (unsigned short*)p; p += (size_t)NKV_H * HD_ * T_SEQ * 2; // 4M

  // 1) converts / transposes
  convert_bf16_kernel<<<(T_SEQ * H_DIM / 4 + 255) / 256, 256, 0, stream>>>(
      hs, hsb, T_SEQ * H_DIM / 4);
  transpose_bf16_kernel<<<dim3(QKV_N / 32, H_DIM / 32), dim3(32, 8), 0, stream>>>(
      w_qkv, wqkvT, H_DIM, QKV_N);
  transpose_bf16_kernel<<<dim3(H_DIM / 32, H_DIM / 32), dim3(32, 8), 0, stream>>>(
      w_o, woT, H_DIM, H_DIM);
  // 2) QKV projection: BN=192 -> grid 32x8 = 256 blocks (full CU coverage)
  gemm256_kernel<3, 4, true><<<dim3(QKV_N / 192, T_SEQ / 256), 512, 0, stream>>>(
      hsb, wqkvT, qkvb, T_SEQ, QKV_N, H_DIM);
  // 3) LN + RoPE (in place; q also scaled by 1/sqrt(HD))
  ln_rope_kernel<<<T_SEQ * (NH_Q + NKV_H) / 4, 256, 0, stream>>>(
      qkvb, positions, q_norm_w, k_norm_w);
  // 4) V transpose for PV B-operand
  vt_kernel<<<dim3(T_SEQ / 32, HD_ / 32, NKV_H), dim3(32, 8), 0, stream>>>(qkvb, vtb);
  // 5) flash attention (paired Q-tiles: uniform work per block)
  attn_kernel<<<dim3(T_SEQ / 128, NH_Q), 256, 0, stream>>>(qkvb, vtb, attnb);
  // 6) output projection: BN=128 -> grid 32x8 = 256 blocks (full CU coverage)
  gemm256_kernel<2, 2, false><<<dim3(H_DIM / 128, T_SEQ / 256), 512, 0, stream>>>(
      attnb, woT, out, T_SEQ, H_DIM, H_DIM);
}